// Round 6
// baseline (226.235 us; speedup 1.0000x reference)
//
#include <hip/hip_runtime.h>
#include <math.h>

#define T_SEQ 2048
#define D_MODEL 2048
#define HEAD_DIM 64
#define N_HEADS 32
#define N_KV 8

using short8 = __attribute__((ext_vector_type(8))) short;
using f32x4  = __attribute__((ext_vector_type(4))) float;
using f32x16 = __attribute__((ext_vector_type(16))) float;
using u32x4  = __attribute__((ext_vector_type(4))) unsigned int;

#define MFMA16(a, b, c) __builtin_amdgcn_mfma_f32_16x16x32_bf16(a, b, c, 0, 0, 0)
#define MFMA32(a, b, c) __builtin_amdgcn_mfma_f32_32x32x16_bf16(a, b, c, 0, 0, 0)

__device__ __forceinline__ unsigned short f2bf(float f) {
    unsigned int u = __builtin_bit_cast(unsigned int, f);
    u += 0x7fff + ((u >> 16) & 1);
    return (unsigned short)(u >> 16);
}
__device__ __forceinline__ void gld_lds16(const ushort* g, ushort* l) {
    __builtin_amdgcn_global_load_lds((const __attribute__((address_space(1))) void*)g,
                                     (__attribute__((address_space(3))) void*)l, 16, 0, 0);
}
// pack two f32 -> one u32 of 2 bf16 (RTNE), single instruction
__device__ __forceinline__ unsigned int cvtpk(float lo, float hi) {
    unsigned int r;
    asm("v_cvt_pk_bf16_f32 %0, %1, %2" : "=v"(r) : "v"(lo), "v"(hi));
    return r;
}
// exchange: a' = {a.lo32, b.lo32 from lane-32}; b' = {a.hi32 from lane+32, b.hi32}
__device__ __forceinline__ void plswap(unsigned int& a, unsigned int& b) {
    auto r = __builtin_amdgcn_permlane32_swap(a, b, false, false);
    a = r[0];
    b = r[1];
}

// ---------------------------------------------------------------------------
// Fused cast (5 fp32->bf16 tensors) + RoPE tables. Rope blocks are the tail
// 256 blocks (grid 14336 + 256).
// ---------------------------------------------------------------------------
__global__ __launch_bounds__(256) void cast_rope_kernel(
    const float* __restrict__ x, const float* __restrict__ wq,
    const float* __restrict__ wk, const float* __restrict__ wv,
    const float* __restrict__ wo,
    ushort* __restrict__ xb, ushort* __restrict__ wqb,
    ushort* __restrict__ wkb, ushort* __restrict__ wvb, ushort* __restrict__ wob,
    float* __restrict__ cosT, float* __restrict__ sinT,
    const int* __restrict__ start_pos, int T) {
    if (blockIdx.x >= 14336) {
        int idx = (blockIdx.x - 14336) * 256 + threadIdx.x;
        int t = idx >> 5;
        int i = idx & 31;
        float pos = (float)(start_pos[0] + t);
        float expo = (float)i / 32.0f;
        float inv_freq = 1.0f / powf(500000.0f, expo);
        const float two_pi = 6.283185307179586f;
        float wavelen = two_pi / inv_freq;
        float inv;
        if (wavelen > 8192.0f) {
            inv = inv_freq / 32.0f;
        } else if (wavelen < 2048.0f) {
            inv = inv_freq;
        } else {
            float smooth = (8192.0f / wavelen - 1.0f) / 3.0f;
            inv = (1.0f - smooth) * (inv_freq / 32.0f) + smooth * inv_freq;
        }
        float ang = pos * inv;
        cosT[i * T + t] = cosf(ang);
        sinT[i * T + t] = sinf(ang);
        return;
    }
    int i = blockIdx.x * 256 + threadIdx.x;
    const float* src; ushort* dst; int off;
    if (i < 1048576)      { src = x;  dst = xb;  off = i; }
    else if (i < 2097152) { src = wq; dst = wqb; off = i - 1048576; }
    else if (i < 2359296) { src = wk; dst = wkb; off = i - 2097152; }
    else if (i < 2621440) { src = wv; dst = wvb; off = i - 2359296; }
    else                  { src = wo; dst = wob; off = i - 2621440; }
    float4 v = ((const float4*)src)[off];
    ushort4 o;
    o.x = f2bf(v.x); o.y = f2bf(v.y); o.z = f2bf(v.z); o.w = f2bf(v.w);
    ((ushort4*)dst)[off] = o;
}

// ---------------------------------------------------------------------------
// Fused QKV GEMM + RoPE epilogue. 64x128 tile, BK=64 as 2x BK=32 sub-tiles
// per barrier, dbuf, XOR-swizzled. Grid 32 x 24 = 768 blocks (3/CU).
// Q outputs are pre-scaled by log2(e)/8 so attention uses a bare exp2.
// ---------------------------------------------------------------------------
__global__ __launch_bounds__(256) void gemm_qkv(
    const ushort* __restrict__ X, const ushort* __restrict__ Wqb,
    const ushort* __restrict__ Wkb, const ushort* __restrict__ Wvb,
    ushort* __restrict__ Qo, ushort* __restrict__ Ko, ushort* __restrict__ Vto,
    const float* __restrict__ cosT, const float* __restrict__ sinT,
    int T, int D) {
    __shared__ __align__(16) ushort As[2][2][2048];   // [buf][sub][64x32]
    __shared__ __align__(16) ushort Bs[2][2][4096];   // [buf][sub][128x32]
    const int tid = threadIdx.x;
    const int w = tid >> 6, l = tid & 63;
    const int m0 = blockIdx.x * 64;
    const int n0g = blockIdx.y * 128;

    const ushort* B;
    ushort* Cout;
    int n0, doRope;
    if (n0g < 2048)      { B = Wqb + (size_t)n0g * D;          Cout = Qo;  n0 = n0g;        doRope = 1; }
    else if (n0g < 2560) { B = Wkb + (size_t)(n0g - 2048) * D; Cout = Ko;  n0 = n0g - 2048; doRope = 1; }
    else                 { B = Wvb + (size_t)(n0g - 2560) * D; Cout = Vto; n0 = n0g - 2560; doRope = 0; }

    const int wm = (w >> 1) * 32, wn = (w & 1) * 64;
    const int lr = l & 15;
    const int quad = l >> 4;

    f32x4 zero = {0.f, 0.f, 0.f, 0.f};
    f32x4 acc[2][4];
#pragma unroll
    for (int i = 0; i < 2; ++i)
#pragma unroll
        for (int j = 0; j < 4; ++j) acc[i][j] = zero;

    const int srow = l >> 2;                       // 0..15
    const int scg  = ((l & 3) ^ (srow & 3)) * 8;   // swizzled global chunk
    const ushort* Ag  = X + (size_t)(m0 + 16 * w + srow) * D + scg;
    const ushort* Bg0 = B + (size_t)(16 * (2 * w) + srow) * D + scg;
    const ushort* Bg1 = B + (size_t)(16 * (2 * w + 1) + srow) * D + scg;

#define GSTAGE(k0v, nb) { \
    gld_lds16(Ag  + (k0v),      &As[nb][0][w * 512]); \
    gld_lds16(Ag  + (k0v) + 32, &As[nb][1][w * 512]); \
    gld_lds16(Bg0 + (k0v),      &Bs[nb][0][(2 * w) * 512]); \
    gld_lds16(Bg0 + (k0v) + 32, &Bs[nb][1][(2 * w) * 512]); \
    gld_lds16(Bg1 + (k0v),      &Bs[nb][0][(2 * w + 1) * 512]); \
    gld_lds16(Bg1 + (k0v) + 32, &Bs[nb][1][(2 * w + 1) * 512]); }

    GSTAGE(0, 0);

    const int rsw = (quad ^ (lr & 3)) * 8;
    for (int k0 = 0; k0 < D; k0 += 64) {
        const int b = (k0 >> 6) & 1;
        __syncthreads();
        if (k0 + 64 < D) GSTAGE(k0 + 64, b ^ 1);
#pragma unroll
        for (int sub = 0; sub < 2; ++sub) {
            short8 af[2], bf[4];
#pragma unroll
            for (int i = 0; i < 2; ++i) af[i] = *(const short8*)&As[b][sub][(wm + i * 16 + lr) * 32 + rsw];
#pragma unroll
            for (int j = 0; j < 4; ++j) bf[j] = *(const short8*)&Bs[b][sub][(wn + j * 16 + lr) * 32 + rsw];
#pragma unroll
            for (int i = 0; i < 2; ++i)
#pragma unroll
                for (int j = 0; j < 4; ++j)
                    acc[i][j] = MFMA16(af[i], bf[j], acc[i][j]);
        }
    }
#undef GSTAGE

    const int mbase = m0 + wm + quad * 4;
    if (doRope) {
        // fold softmax scale (1/8) and log2(e) into Q only
        const float qsc = (n0g < 2048) ? 0.18033688011112042f : 1.0f;
#pragma unroll
        for (int i = 0; i < 2; ++i) {
            int trow = mbase + i * 16;
#pragma unroll
            for (int j = 0; j < 2; ++j) {
                int i1 = lr + j * 16;
                float4 c4 = *(const float4*)&cosT[(size_t)i1 * T + trow];
                float4 s4 = *(const float4*)&sinT[(size_t)i1 * T + trow];
                int n1 = n0 + wn + lr + j * 16;
                int n2 = n1 + 32;
                size_t b1 = (size_t)(n1 >> 6) * ((size_t)T * 64) + (size_t)(n1 & 63);
                size_t b2 = (size_t)(n2 >> 6) * ((size_t)T * 64) + (size_t)(n2 & 63);
                float cs[4] = {c4.x, c4.y, c4.z, c4.w};
                float sn[4] = {s4.x, s4.y, s4.z, s4.w};
#pragma unroll
                for (int r = 0; r < 4; ++r) {
                    float x1 = acc[i][j][r], x2 = acc[i][j + 2][r];
                    Cout[b1 + (size_t)(trow + r) * 64] = f2bf((x1 * cs[r] - x2 * sn[r]) * qsc);
                    Cout[b2 + (size_t)(trow + r) * 64] = f2bf((x2 * cs[r] + x1 * sn[r]) * qsc);
                }
            }
        }
    } else {
#pragma unroll
        for (int i = 0; i < 2; ++i)
#pragma unroll
            for (int j = 0; j < 4; ++j) {
                int n = n0 + wn + lr + j * 16;
                int m = mbase + i * 16;
                ushort4 o;
                o.x = f2bf(acc[i][j][0]); o.y = f2bf(acc[i][j][1]);
                o.z = f2bf(acc[i][j][2]); o.w = f2bf(acc[i][j][3]);
                *(ushort4*)&Vto[(size_t)n * T + m] = o;
            }
    }
}

// ---------------------------------------------------------------------------
// Output projection GEMM (C fp32), same BK=64 dual-sub-tile core
// ---------------------------------------------------------------------------
__global__ __launch_bounds__(256) void gemm_bt_f32(const ushort* __restrict__ A,
                                                   const ushort* __restrict__ B,
                                                   float* __restrict__ C,
                                                   int M, int N, int K) {
    __shared__ __align__(16) ushort As[2][2][2048];
    __shared__ __align__(16) ushort Bs[2][2][4096];
    const int tid = threadIdx.x;
    const int w = tid >> 6, l = tid & 63;
    const int m0 = blockIdx.x * 64, n0 = blockIdx.y * 128;
    const int wm = (w >> 1) * 32, wn = (w & 1) * 64;
    const int lr = l & 15;
    const int quad = l >> 4;

    f32x4 zero = {0.f, 0.f, 0.f, 0.f};
    f32x4 acc[2][4];
#pragma unroll
    for (int i = 0; i < 2; ++i)
#pragma unroll
        for (int j = 0; j < 4; ++j) acc[i][j] = zero;

    const int srow = l >> 2;
    const int scg  = ((l & 3) ^ (srow & 3)) * 8;
    const ushort* Ag  = A + (size_t)(m0 + 16 * w + srow) * K + scg;
    const ushort* Bg0 = B + (size_t)(n0 + 16 * (2 * w) + srow) * K + scg;
    const ushort* Bg1 = B + (size_t)(n0 + 16 * (2 * w + 1) + srow) * K + scg;

#define GSTAGE(k0v, nb) { \
    gld_lds16(Ag  + (k0v),      &As[nb][0][w * 512]); \
    gld_lds16(Ag  + (k0v) + 32, &As[nb][1][w * 512]); \
    gld_lds16(Bg0 + (k0v),      &Bs[nb][0][(2 * w) * 512]); \
    gld_lds16(Bg0 + (k0v) + 32, &Bs[nb][1][(2 * w) * 512]); \
    gld_lds16(Bg1 + (k0v),      &Bs[nb][0][(2 * w + 1) * 512]); \
    gld_lds16(Bg1 + (k0v) + 32, &Bs[nb][1][(2 * w + 1) * 512]); }

    GSTAGE(0, 0);

    const int rsw = (quad ^ (lr & 3)) * 8;
    for (int k0 = 0; k0 < K; k0 += 64) {
        const int b = (k0 >> 6) & 1;
        __syncthreads();
        if (k0 + 64 < K) GSTAGE(k0 + 64, b ^ 1);
#pragma unroll
        for (int sub = 0; sub < 2; ++sub) {
            short8 af[2], bf[4];
#pragma unroll
            for (int i = 0; i < 2; ++i) af[i] = *(const short8*)&As[b][sub][(wm + i * 16 + lr) * 32 + rsw];
#pragma unroll
            for (int j = 0; j < 4; ++j) bf[j] = *(const short8*)&Bs[b][sub][(wn + j * 16 + lr) * 32 + rsw];
#pragma unroll
            for (int i = 0; i < 2; ++i)
#pragma unroll
                for (int j = 0; j < 4; ++j)
                    acc[i][j] = MFMA16(af[i], bf[j], acc[i][j]);
        }
    }
#undef GSTAGE

    const int mbase = m0 + wm + quad * 4;
    const int nbase = n0 + wn + lr;
#pragma unroll
    for (int i = 0; i < 2; ++i)
#pragma unroll
        for (int j = 0; j < 4; ++j)
#pragma unroll
            for (int r = 0; r < 4; ++r)
                C[(size_t)(mbase + i * 16 + r) * N + (nbase + j * 16)] = acc[i][j][r];
}

// ---------------------------------------------------------------------------
// Flash attention v7: SPLIT-K. No running max in this softmax (pure exp2 +
// sum), so key-chunk partials are purely additive -> split each (hp, qt)
// into chunks of <=8 k-tiles (512 keys). Longest serial chain: 32 -> 8 steps.
//   1280 blocks, LPT order (full 8-step chunks first):
//     band3 (qt 31..24, 4 chunks) 512 | band2 (23..16, 3) 384 |
//     band1 (15..8, 2) 256 | band0 (7..0, 1) 128.
//   LDS dbuf 32 KB (K 2-ahead, V 1-ahead), launch_bounds(256,3) ->
//   3 blocks/CU resident. One vmcnt(0)+barrier per iter (each wave certifies
//   its own gld_lds writes BEFORE the barrier -> cross-wave safe; every load
//   has a full iteration to land, so the drain is cheap -- R4 measured
//   counted-vs-drain as neutral here).
//   Epilogue: fp32 atomicAdd partial O^T into ctxT[hd][t] (lanes hit 32
//   consecutive floats -> coalesced bursts) + lsum into lacc[h][t].
//   exp2 computed in-place into s_cur (saves 32 VGPRs).
// ---------------------------------------------------------------------------
__global__ __launch_bounds__(256, 3) void attn_mfma(const ushort* __restrict__ Q,
                                                    const ushort* __restrict__ K,
                                                    const ushort* __restrict__ Vt,
                                                    float* __restrict__ ctxT,
                                                    float* __restrict__ lacc, int T) {
    __shared__ __align__(16) ushort Ks[2][4096];   // [key64][dim64], chunk-swizzled
    __shared__ __align__(16) ushort Vs[2][4096];   // [dim64][key64], chunk-swizzled
    const int tid = threadIdx.x, w = tid >> 6, l = tid & 63;
    const int lq = l & 31, hi = l >> 5;

    // band decode: bid -> (hp, qt, c)
    const int bid = blockIdx.x;
    int hp, qt, c;
    if (bid < 512)       { int i = bid;        qt = 31 - (i >> 6); hp = (i >> 2) & 15; c = i & 3; }
    else if (bid < 896)  { int i = bid - 512;  qt = 23 - i / 48;   hp = (i / 3) & 15;  c = i % 3; }
    else if (bid < 1152) { int i = bid - 896;  qt = 15 - (i >> 5); hp = (i >> 1) & 15; c = i & 1; }
    else                 { int i = bid - 1152; qt = 7 - (i >> 4);  hp = i & 15;        c = 0; }
    const int t0 = 8 * c;
    const int t1 = (8 * c + 8 < qt + 1) ? (8 * c + 8) : (qt + 1);

    const int hk = hp >> 1;                    // kv-head
    const int h  = 2 * hp + (w & 1);           // this wave's q-head
    const int roff = (w >> 1) * 32;            // row offset within 64-row q-tile
    const int qrow = qt * 64 + roff + lq;      // global q row owned by this lane
    const ushort* Kb = K + (size_t)hk * T * 64;
    const ushort* Vb = Vt + (size_t)hk * 64 * T;

    const int srow = l >> 3;                   // 0..7
    const int sc   = ((l & 7) ^ srow) * 8;     // pre-swizzled global chunk offset

    // Q fragments (B operand): col q = lq, k-dims ks*16 + hi*8 + j
    const ushort* Qrow = Q + ((size_t)h * T + qrow) * 64;
    short8 qf[4];
#pragma unroll
    for (int ks = 0; ks < 4; ++ks)
        qf[ks] = *(const short8*)(Qrow + ks * 16 + hi * 8);

    f32x16 oacc0, oacc1;
#pragma unroll
    for (int r = 0; r < 16; ++r) { oacc0[r] = 0.f; oacc1[r] = 0.f; }
    float ls[4] = {0.f, 0.f, 0.f, 0.f};

    // wave w stages K chunks {2w,2w+1} / V chunks {2w,2w+1} (1KB each)
#define KSTAGE(kt, buf) do { \
    size_t _k0 = (size_t)(kt) * 64; \
    gld_lds16(Kb + (_k0 + (2 * w) * 8 + srow) * 64 + sc,     &Ks[buf][(2 * w) * 512]); \
    gld_lds16(Kb + (_k0 + (2 * w + 1) * 8 + srow) * 64 + sc, &Ks[buf][(2 * w + 1) * 512]); \
} while (0)
#define VSTAGE(kt, buf) do { \
    size_t _k0 = (size_t)(kt) * 64; \
    gld_lds16(Vb + (size_t)((2 * w) * 8 + srow) * T + _k0 + sc,     &Vs[buf][(2 * w) * 512]); \
    gld_lds16(Vb + (size_t)((2 * w + 1) * 8 + srow) * T + _k0 + sc, &Vs[buf][(2 * w + 1) * 512]); \
} while (0)

    // QK cluster: S^T = K @ Q^T into (sd0, sd1) from Ks[bn]; skip1 skips keys+32
#define QKT(bn, sd0, sd1, skip1) do { \
    __builtin_amdgcn_s_setprio(1); \
    _Pragma("unroll") \
    for (int ks = 0; ks < 4; ++ks) { \
        const int cc = ((ks * 2 + hi) ^ (lq & 7)) * 8; \
        short8 kf0 = *(const short8*)&Ks[bn][lq * 64 + cc]; \
        sd0 = MFMA32(kf0, qf[ks], sd0); \
    } \
    if (!(skip1)) { \
        _Pragma("unroll") \
        for (int ks = 0; ks < 4; ++ks) { \
            const int cc = ((ks * 2 + hi) ^ (lq & 7)) * 8; \
            short8 kf1 = *(const short8*)&Ks[bn][(lq + 32) * 64 + cc]; \
            sd1 = MFMA32(kf1, qf[ks], sd1); \
        } \
    } \
    __builtin_amdgcn_s_setprio(0); \
} while (0)

    // prologue: K(t0) [+K(t0+1)] + V(t0); certify own K(t0); barrier; QK(t0)
    KSTAGE(t0, 0);
    const bool two = (t0 + 1 < t1);
    if (two) KSTAGE(t0 + 1, 1);
    VSTAGE(t0, 0);
    if (two) asm volatile("s_waitcnt vmcnt(4)" ::: "memory");
    else     asm volatile("s_waitcnt vmcnt(2)" ::: "memory");
    __builtin_amdgcn_s_barrier();
    __builtin_amdgcn_sched_barrier(0);

    f32x16 s_cur0, s_cur1, s_next0, s_next1;
#pragma unroll
    for (int r = 0; r < 16; ++r) { s_cur0[r] = 0.f; s_cur1[r] = 0.f; }
    QKT(0, s_cur0, s_cur1, (t0 == qt) && (roff == 0));

    for (int kt = t0; kt < t1; ++kt) {
        const int b = kt & 1;
        // certify ALL own outstanding stage loads (tile kt's V, tile kt+1's K)
        // BEFORE the rendezvous -> everything staged so far is cross-wave safe.
        asm volatile("s_waitcnt vmcnt(0)" ::: "memory");
        __builtin_amdgcn_s_barrier();
        __builtin_amdgcn_sched_barrier(0);

        const bool lastg = (kt == qt);
        const bool halfT = lastg && (roff == 0);   // keys kt*64+32.. all masked

        // QK of NEXT tile (independent of this tile's softmax/PV)
        if (kt + 1 < t1) {
#pragma unroll
            for (int r = 0; r < 16; ++r) { s_next0[r] = 0.f; s_next1[r] = 0.f; }
            QKT(b ^ 1, s_next0, s_next1, ((kt + 1) == qt) && (roff == 0));
        }
        // stage ahead: K 2-ahead into Ks[b] (K(kt) dead), V 1-ahead into Vs[b^1]
        if (kt + 2 < t1) KSTAGE(kt + 2, b);
        if (kt + 1 < t1) VSTAGE(kt + 1, b ^ 1);

        // p = exp2(s_cur) in place (Q pre-scaled by log2e/8); mask on diag tile
        const int k0 = kt * 64;
        if (lastg) {
            if (roff == 0) {
#pragma unroll
                for (int r = 0; r < 16; ++r) {
                    const int kk = k0 + (r & 3) + 8 * (r >> 2) + 4 * hi;
                    s_cur0[r] = (kk <= qrow) ? __builtin_amdgcn_exp2f(s_cur0[r]) : 0.f;
                }
            } else {
#pragma unroll
                for (int r = 0; r < 16; ++r) s_cur0[r] = __builtin_amdgcn_exp2f(s_cur0[r]);
#pragma unroll
                for (int r = 0; r < 16; ++r) {
                    const int kk = k0 + 32 + (r & 3) + 8 * (r >> 2) + 4 * hi;
                    s_cur1[r] = (kk <= qrow) ? __builtin_amdgcn_exp2f(s_cur1[r]) : 0.f;
                }
            }
        } else {
#pragma unroll
            for (int r = 0; r < 16; ++r) s_cur0[r] = __builtin_amdgcn_exp2f(s_cur0[r]);
#pragma unroll
            for (int r = 0; r < 16; ++r) s_cur1[r] = __builtin_amdgcn_exp2f(s_cur1[r]);
        }
#pragma unroll
        for (int r = 0; r < 16; ++r) ls[r & 3] += s_cur0[r];
        if (!halfT) {
#pragma unroll
            for (int r = 0; r < 16; ++r) ls[r & 3] += s_cur1[r];
        }

        // O^T += V^T @ P^T; P B-frags built in-register (cvt_pk + permlane32)
        const int nks2 = halfT ? 2 : 4;
        __builtin_amdgcn_s_setprio(1);
        for (int ks2 = 0; ks2 < nks2; ++ks2) {
            const f32x16& pp = (ks2 < 2) ? s_cur0 : s_cur1;
            const int bse = (ks2 & 1) * 8;
            unsigned int a0 = cvtpk(pp[bse + 0], pp[bse + 1]);
            unsigned int a1 = cvtpk(pp[bse + 2], pp[bse + 3]);
            unsigned int b0 = cvtpk(pp[bse + 4], pp[bse + 5]);
            unsigned int b1 = cvtpk(pp[bse + 6], pp[bse + 7]);
            plswap(a0, b0);
            plswap(a1, b1);
            u32x4 tw = {a0, a1, b0, b1};
            short8 pf = __builtin_bit_cast(short8, tw);
            const int cc = ((ks2 * 2 + hi) ^ (lq & 7)) * 8;
            short8 vf0 = *(const short8*)&Vs[b][lq * 64 + cc];
            short8 vf1 = *(const short8*)&Vs[b][(lq + 32) * 64 + cc];
            oacc0 = MFMA32(vf0, pf, oacc0);
            oacc1 = MFMA32(vf1, pf, oacc1);
        }
        __builtin_amdgcn_s_setprio(0);

        s_cur0 = s_next0;
        s_cur1 = s_next1;
    }
#undef QKT
#undef KSTAGE
#undef VSTAGE

    // partial row sum for q-row lq (this chunk's keys)
    float vsum = (ls[0] + ls[1]) + (ls[2] + ls[3]);
    vsum += __shfl_xor(vsum, 32, 64);
    if (hi == 0) atomicAdd(&lacc[(size_t)h * 2048 + qrow], vsum);

    // partial O^T: ctxT[(h*64+d)][qrow]; lanes of a half-wave hit 32
    // consecutive floats -> coalesced atomic bursts.
    float* cb = ctxT + (size_t)(h * 64) * 2048 + qrow;
#pragma unroll
    for (int r = 0; r < 16; ++r) {
        const int d = (r & 3) + 8 * (r >> 2) + 4 * hi;
        atomicAdd(cb + (size_t)d * 2048, oacc0[r]);
        atomicAdd(cb + (size_t)(d + 32) * 2048, oacc1[r]);
    }
}

// ---------------------------------------------------------------------------
// Normalize + transpose: ctxb[t][hd] = ctxT[hd][t] / lacc[hd>>6][t], bf16.
// 64x64 tiles via LDS (pad 65 -> 2-way conflicts only, free).
// ---------------------------------------------------------------------------
__global__ __launch_bounds__(256) void norm_ctx(const float* __restrict__ cT,
                                                const float* __restrict__ lacc,
                                                ushort* __restrict__ ctxb) {
    __shared__ float tile[64][65];
    const int tau = threadIdx.x;
    const int t0 = blockIdx.x * 64;
    const int hd0 = blockIdx.y * 64;   // one head per tile (64 | head width)
    {
        const int r = tau >> 2, cq = tau & 3;
        const float* src = cT + (size_t)(hd0 + r) * 2048 + t0 + cq * 16;
#pragma unroll
        for (int j = 0; j < 4; ++j) {
            float4 v = *(const float4*)(src + j * 4);
            tile[r][cq * 16 + j * 4 + 0] = v.x;
            tile[r][cq * 16 + j * 4 + 1] = v.y;
            tile[r][cq * 16 + j * 4 + 2] = v.z;
            tile[r][cq * 16 + j * 4 + 3] = v.w;
        }
    }
    __syncthreads();
    const int tt = tau >> 2, rq = tau & 3;
    const float invl = 1.0f / lacc[(size_t)(hd0 >> 6) * 2048 + t0 + tt];
    ushort* dst = ctxb + (size_t)(t0 + tt) * 2048 + hd0 + rq * 16;
#pragma unroll
    for (int j = 0; j < 4; ++j) {
        ushort4 o;
        o.x = f2bf(tile[rq * 16 + j * 4 + 0][tt] * invl);
        o.y = f2bf(tile[rq * 16 + j * 4 + 1][tt] * invl);
        o.z = f2bf(tile[rq * 16 + j * 4 + 2][tt] * invl);
        o.w = f2bf(tile[rq * 16 + j * 4 + 3][tt] * invl);
        *(ushort4*)(dst + j * 4) = o;
    }
}

// ---------------------------------------------------------------------------
extern "C" void kernel_launch(void* const* d_in, const int* in_sizes, int n_in,
                              void* d_out, int out_size, void* d_ws, size_t ws_size,
                              hipStream_t stream) {
    const float* x  = (const float*)d_in[0];
    const float* Wq = (const float*)d_in[1];
    const float* Wk = (const float*)d_in[2];
    const float* Wv = (const float*)d_in[3];
    const float* Wo = (const float*)d_in[4];
    const int* start_pos = (const int*)d_in[5];
    float* out = (float*)d_out;

    const int T = T_SEQ, D = D_MODEL;
    const int KV = N_KV * HEAD_DIM;  // 512

    char* w = (char*)d_ws;
    float* cosT = (float*)w;            w += (size_t)32 * T * 4;
    float* sinT = (float*)w;            w += (size_t)32 * T * 4;
    ushort* xbf  = (ushort*)w;          w += (size_t)T * D * 2;
    ushort* wqbf = (ushort*)w;          w += (size_t)D * D * 2;
    ushort* wkbf = (ushort*)w;          w += (size_t)KV * D * 2;
    ushort* wvbf = (ushort*)w;          w += (size_t)KV * D * 2;
    ushort* wobf = (ushort*)w;          w += (size_t)D * D * 2;
    ushort* qbf  = (ushort*)w;          w += (size_t)N_HEADS * T * 64 * 2;
    ushort* kbf  = (ushort*)w;          w += (size_t)N_KV * T * 64 * 2;
    ushort* vtbf = (ushort*)w;          w += (size_t)N_KV * 64 * T * 2;

    // fp32 O^T accumulator (16 MB) aliases xbf+wqbf (dead after gemm_qkv);
    // lacc (256 KB) aliases wkbf head; bf16 ctx aliases qbf (dead after attn).
    float* ctx32T = (float*)xbf;
    float* lacc   = (float*)wkbf;
    ushort* ctxbf = qbf;

    cast_rope_kernel<<<dim3(14336 + 256), dim3(256), 0, stream>>>(
        x, Wq, Wk, Wv, Wo, xbf, wqbf, wkbf, wvbf, wobf, cosT, sinT, start_pos, T);

    gemm_qkv<<<dim3(T / 64, (D + 2 * KV) / 128), dim3(256), 0, stream>>>(
        xbf, wqbf, wkbf, wvbf, qbf, kbf, vtbf, cosT, sinT, T, D);

    // zero the partial accumulators (ctx32T and lacc are contiguous)
    hipMemsetAsync(ctx32T, 0, (size_t)2048 * 2048 * 4 + (size_t)32 * 2048 * 4, stream);

    attn_mfma<<<dim3(1280), dim3(256), 0, stream>>>(qbf, kbf, vtbf, ctx32T, lacc, T);

    norm_ctx<<<dim3(32, 32), dim3(256), 0, stream>>>(ctx32T, lacc, ctxbf);

    gemm_bt_f32<<<dim3(T / 64, D / 128), dim3(256), 0, stream>>>(ctxbf, wobf, out, T, D, D);
}

// Round 7
// 202.702 us; speedup vs baseline: 1.1161x; 1.1161x over previous
//
#include <hip/hip_runtime.h>
#include <math.h>

#define T_SEQ 2048
#define D_MODEL 2048
#define HEAD_DIM 64
#define N_HEADS 32
#define N_KV 8

using short8 = __attribute__((ext_vector_type(8))) short;
using f32x4  = __attribute__((ext_vector_type(4))) float;
using f32x16 = __attribute__((ext_vector_type(16))) float;
using u32x4  = __attribute__((ext_vector_type(4))) unsigned int;

#define MFMA16(a, b, c) __builtin_amdgcn_mfma_f32_16x16x32_bf16(a, b, c, 0, 0, 0)
#define MFMA32(a, b, c) __builtin_amdgcn_mfma_f32_32x32x16_bf16(a, b, c, 0, 0, 0)

__device__ __forceinline__ unsigned short f2bf(float f) {
    unsigned int u = __builtin_bit_cast(unsigned int, f);
    u += 0x7fff + ((u >> 16) & 1);
    return (unsigned short)(u >> 16);
}
__device__ __forceinline__ void gld_lds16(const ushort* g, ushort* l) {
    __builtin_amdgcn_global_load_lds((const __attribute__((address_space(1))) void*)g,
                                     (__attribute__((address_space(3))) void*)l, 16, 0, 0);
}
// pack two f32 -> one u32 of 2 bf16 (RTNE), single instruction
__device__ __forceinline__ unsigned int cvtpk(float lo, float hi) {
    unsigned int r;
    asm("v_cvt_pk_bf16_f32 %0, %1, %2" : "=v"(r) : "v"(lo), "v"(hi));
    return r;
}
// exchange: a' = {a.lo32, b.lo32 from lane-32}; b' = {a.hi32 from lane+32, b.hi32}
__device__ __forceinline__ void plswap(unsigned int& a, unsigned int& b) {
    auto r = __builtin_amdgcn_permlane32_swap(a, b, false, false);
    a = r[0];
    b = r[1];
}

// ---------------------------------------------------------------------------
// Fused cast (5 fp32->bf16 tensors) + RoPE tables. Rope blocks are the tail
// 256 blocks (grid 14336 + 256).
// ---------------------------------------------------------------------------
__global__ __launch_bounds__(256) void cast_rope_kernel(
    const float* __restrict__ x, const float* __restrict__ wq,
    const float* __restrict__ wk, const float* __restrict__ wv,
    const float* __restrict__ wo,
    ushort* __restrict__ xb, ushort* __restrict__ wqb,
    ushort* __restrict__ wkb, ushort* __restrict__ wvb, ushort* __restrict__ wob,
    float* __restrict__ cosT, float* __restrict__ sinT,
    const int* __restrict__ start_pos, int T) {
    if (blockIdx.x >= 14336) {
        int idx = (blockIdx.x - 14336) * 256 + threadIdx.x;
        int t = idx >> 5;
        int i = idx & 31;
        float pos = (float)(start_pos[0] + t);
        float expo = (float)i / 32.0f;
        float inv_freq = 1.0f / powf(500000.0f, expo);
        const float two_pi = 6.283185307179586f;
        float wavelen = two_pi / inv_freq;
        float inv;
        if (wavelen > 8192.0f) {
            inv = inv_freq / 32.0f;
        } else if (wavelen < 2048.0f) {
            inv = inv_freq;
        } else {
            float smooth = (8192.0f / wavelen - 1.0f) / 3.0f;
            inv = (1.0f - smooth) * (inv_freq / 32.0f) + smooth * inv_freq;
        }
        float ang = pos * inv;
        cosT[i * T + t] = cosf(ang);
        sinT[i * T + t] = sinf(ang);
        return;
    }
    int i = blockIdx.x * 256 + threadIdx.x;
    const float* src; ushort* dst; int off;
    if (i < 1048576)      { src = x;  dst = xb;  off = i; }
    else if (i < 2097152) { src = wq; dst = wqb; off = i - 1048576; }
    else if (i < 2359296) { src = wk; dst = wkb; off = i - 2097152; }
    else if (i < 2621440) { src = wv; dst = wvb; off = i - 2359296; }
    else                  { src = wo; dst = wob; off = i - 2621440; }
    float4 v = ((const float4*)src)[off];
    ushort4 o;
    o.x = f2bf(v.x); o.y = f2bf(v.y); o.z = f2bf(v.z); o.w = f2bf(v.w);
    ((ushort4*)dst)[off] = o;
}

// ---------------------------------------------------------------------------
// Fused QKV GEMM + RoPE epilogue. 64x128 tile, BK=64 as 2x BK=32 sub-tiles
// per barrier, dbuf, XOR-swizzled. Grid 32 x 24 = 768 blocks (3/CU).
// Q outputs are pre-scaled by log2(e)/8 so attention uses a bare exp2.
// ---------------------------------------------------------------------------
__global__ __launch_bounds__(256) void gemm_qkv(
    const ushort* __restrict__ X, const ushort* __restrict__ Wqb,
    const ushort* __restrict__ Wkb, const ushort* __restrict__ Wvb,
    ushort* __restrict__ Qo, ushort* __restrict__ Ko, ushort* __restrict__ Vto,
    const float* __restrict__ cosT, const float* __restrict__ sinT,
    int T, int D) {
    __shared__ __align__(16) ushort As[2][2][2048];   // [buf][sub][64x32]
    __shared__ __align__(16) ushort Bs[2][2][4096];   // [buf][sub][128x32]
    const int tid = threadIdx.x;
    const int w = tid >> 6, l = tid & 63;
    const int m0 = blockIdx.x * 64;
    const int n0g = blockIdx.y * 128;

    const ushort* B;
    ushort* Cout;
    int n0, doRope;
    if (n0g < 2048)      { B = Wqb + (size_t)n0g * D;          Cout = Qo;  n0 = n0g;        doRope = 1; }
    else if (n0g < 2560) { B = Wkb + (size_t)(n0g - 2048) * D; Cout = Ko;  n0 = n0g - 2048; doRope = 1; }
    else                 { B = Wvb + (size_t)(n0g - 2560) * D; Cout = Vto; n0 = n0g - 2560; doRope = 0; }

    const int wm = (w >> 1) * 32, wn = (w & 1) * 64;
    const int lr = l & 15;
    const int quad = l >> 4;

    f32x4 zero = {0.f, 0.f, 0.f, 0.f};
    f32x4 acc[2][4];
#pragma unroll
    for (int i = 0; i < 2; ++i)
#pragma unroll
        for (int j = 0; j < 4; ++j) acc[i][j] = zero;

    const int srow = l >> 2;                       // 0..15
    const int scg  = ((l & 3) ^ (srow & 3)) * 8;   // swizzled global chunk
    const ushort* Ag  = X + (size_t)(m0 + 16 * w + srow) * D + scg;
    const ushort* Bg0 = B + (size_t)(16 * (2 * w) + srow) * D + scg;
    const ushort* Bg1 = B + (size_t)(16 * (2 * w + 1) + srow) * D + scg;

#define GSTAGE(k0v, nb) { \
    gld_lds16(Ag  + (k0v),      &As[nb][0][w * 512]); \
    gld_lds16(Ag  + (k0v) + 32, &As[nb][1][w * 512]); \
    gld_lds16(Bg0 + (k0v),      &Bs[nb][0][(2 * w) * 512]); \
    gld_lds16(Bg0 + (k0v) + 32, &Bs[nb][1][(2 * w) * 512]); \
    gld_lds16(Bg1 + (k0v),      &Bs[nb][0][(2 * w + 1) * 512]); \
    gld_lds16(Bg1 + (k0v) + 32, &Bs[nb][1][(2 * w + 1) * 512]); }

    GSTAGE(0, 0);

    const int rsw = (quad ^ (lr & 3)) * 8;
    for (int k0 = 0; k0 < D; k0 += 64) {
        const int b = (k0 >> 6) & 1;
        __syncthreads();
        if (k0 + 64 < D) GSTAGE(k0 + 64, b ^ 1);
#pragma unroll
        for (int sub = 0; sub < 2; ++sub) {
            short8 af[2], bf[4];
#pragma unroll
            for (int i = 0; i < 2; ++i) af[i] = *(const short8*)&As[b][sub][(wm + i * 16 + lr) * 32 + rsw];
#pragma unroll
            for (int j = 0; j < 4; ++j) bf[j] = *(const short8*)&Bs[b][sub][(wn + j * 16 + lr) * 32 + rsw];
#pragma unroll
            for (int i = 0; i < 2; ++i)
#pragma unroll
                for (int j = 0; j < 4; ++j)
                    acc[i][j] = MFMA16(af[i], bf[j], acc[i][j]);
        }
    }
#undef GSTAGE

    const int mbase = m0 + wm + quad * 4;
    if (doRope) {
        // fold softmax scale (1/8) and log2(e) into Q only
        const float qsc = (n0g < 2048) ? 0.18033688011112042f : 1.0f;
#pragma unroll
        for (int i = 0; i < 2; ++i) {
            int trow = mbase + i * 16;
#pragma unroll
            for (int j = 0; j < 2; ++j) {
                int i1 = lr + j * 16;
                float4 c4 = *(const float4*)&cosT[(size_t)i1 * T + trow];
                float4 s4 = *(const float4*)&sinT[(size_t)i1 * T + trow];
                int n1 = n0 + wn + lr + j * 16;
                int n2 = n1 + 32;
                size_t b1 = (size_t)(n1 >> 6) * ((size_t)T * 64) + (size_t)(n1 & 63);
                size_t b2 = (size_t)(n2 >> 6) * ((size_t)T * 64) + (size_t)(n2 & 63);
                float cs[4] = {c4.x, c4.y, c4.z, c4.w};
                float sn[4] = {s4.x, s4.y, s4.z, s4.w};
#pragma unroll
                for (int r = 0; r < 4; ++r) {
                    float x1 = acc[i][j][r], x2 = acc[i][j + 2][r];
                    Cout[b1 + (size_t)(trow + r) * 64] = f2bf((x1 * cs[r] - x2 * sn[r]) * qsc);
                    Cout[b2 + (size_t)(trow + r) * 64] = f2bf((x2 * cs[r] + x1 * sn[r]) * qsc);
                }
            }
        }
    } else {
#pragma unroll
        for (int i = 0; i < 2; ++i)
#pragma unroll
            for (int j = 0; j < 4; ++j) {
                int n = n0 + wn + lr + j * 16;
                int m = mbase + i * 16;
                ushort4 o;
                o.x = f2bf(acc[i][j][0]); o.y = f2bf(acc[i][j][1]);
                o.z = f2bf(acc[i][j][2]); o.w = f2bf(acc[i][j][3]);
                *(ushort4*)&Vto[(size_t)n * T + m] = o;
            }
    }
}

// ---------------------------------------------------------------------------
// Output projection GEMM (C fp32), same BK=64 dual-sub-tile core
// ---------------------------------------------------------------------------
__global__ __launch_bounds__(256) void gemm_bt_f32(const ushort* __restrict__ A,
                                                   const ushort* __restrict__ B,
                                                   float* __restrict__ C,
                                                   int M, int N, int K) {
    __shared__ __align__(16) ushort As[2][2][2048];
    __shared__ __align__(16) ushort Bs[2][2][4096];
    const int tid = threadIdx.x;
    const int w = tid >> 6, l = tid & 63;
    const int m0 = blockIdx.x * 64, n0 = blockIdx.y * 128;
    const int wm = (w >> 1) * 32, wn = (w & 1) * 64;
    const int lr = l & 15;
    const int quad = l >> 4;

    f32x4 zero = {0.f, 0.f, 0.f, 0.f};
    f32x4 acc[2][4];
#pragma unroll
    for (int i = 0; i < 2; ++i)
#pragma unroll
        for (int j = 0; j < 4; ++j) acc[i][j] = zero;

    const int srow = l >> 2;
    const int scg  = ((l & 3) ^ (srow & 3)) * 8;
    const ushort* Ag  = A + (size_t)(m0 + 16 * w + srow) * K + scg;
    const ushort* Bg0 = B + (size_t)(n0 + 16 * (2 * w) + srow) * K + scg;
    const ushort* Bg1 = B + (size_t)(n0 + 16 * (2 * w + 1) + srow) * K + scg;

#define GSTAGE(k0v, nb) { \
    gld_lds16(Ag  + (k0v),      &As[nb][0][w * 512]); \
    gld_lds16(Ag  + (k0v) + 32, &As[nb][1][w * 512]); \
    gld_lds16(Bg0 + (k0v),      &Bs[nb][0][(2 * w) * 512]); \
    gld_lds16(Bg0 + (k0v) + 32, &Bs[nb][1][(2 * w) * 512]); \
    gld_lds16(Bg1 + (k0v),      &Bs[nb][0][(2 * w + 1) * 512]); \
    gld_lds16(Bg1 + (k0v) + 32, &Bs[nb][1][(2 * w + 1) * 512]); }

    GSTAGE(0, 0);

    const int rsw = (quad ^ (lr & 3)) * 8;
    for (int k0 = 0; k0 < K; k0 += 64) {
        const int b = (k0 >> 6) & 1;
        __syncthreads();
        if (k0 + 64 < K) GSTAGE(k0 + 64, b ^ 1);
#pragma unroll
        for (int sub = 0; sub < 2; ++sub) {
            short8 af[2], bf[4];
#pragma unroll
            for (int i = 0; i < 2; ++i) af[i] = *(const short8*)&As[b][sub][(wm + i * 16 + lr) * 32 + rsw];
#pragma unroll
            for (int j = 0; j < 4; ++j) bf[j] = *(const short8*)&Bs[b][sub][(wn + j * 16 + lr) * 32 + rsw];
#pragma unroll
            for (int i = 0; i < 2; ++i)
#pragma unroll
                for (int j = 0; j < 4; ++j)
                    acc[i][j] = MFMA16(af[i], bf[j], acc[i][j]);
        }
    }
#undef GSTAGE

    const int mbase = m0 + wm + quad * 4;
    const int nbase = n0 + wn + lr;
#pragma unroll
    for (int i = 0; i < 2; ++i)
#pragma unroll
        for (int j = 0; j < 4; ++j)
#pragma unroll
            for (int r = 0; r < 4; ++r)
                C[(size_t)(mbase + i * 16 + r) * N + (nbase + j * 16)] = acc[i][j][r];
}

// ---------------------------------------------------------------------------
// Flash attention v8: R3 head-pair core with KVBLK=128 (two 64-key tiles per
// barrier). Every prior variant (R0-R6) kept 64 keys/barrier and ~32 steps
// and all landed at 42-48 us regardless of sync scheme -> per-step FIXED
// overhead (rendezvous + drain + refill) dominates. This halves the step
// count: nsteps = (qt+2)/2, max 16.
//   LDS: [buf][half] pairs of the existing 64-key layouts (64 KB total,
//   2 blocks/CU as before). Per step: __syncthreads once, stage the next
//   128-key pair, compute both halves with the verified R3 tile body.
//   Tile-granular causal skip: second half skipped by wave-uniform guard
//   when fully masked; diag-tile mask/half-skip logic unchanged (t == qt).
//   Blocks: 256 thr, wave w -> head 2*hp+(w&1), q-rows roff=(w>>1)*32.
//   Pairing {qt, 31-qt} per CU via (hp>>3)&1 (validated R3).
// ---------------------------------------------------------------------------
__global__ __launch_bounds__(256, 2) void attn_mfma(const ushort* __restrict__ Q,
                                                    const ushort* __restrict__ K,
                                                    const ushort* __restrict__ Vt,
                                                    ushort* __restrict__ ctx, int T) {
    __shared__ __align__(16) ushort Ks[2][2][4096];   // [buf][half][key64][dim64]
    __shared__ __align__(16) ushort Vs[2][2][4096];   // [buf][half][dim64][key64]
    const int tid = threadIdx.x, w = tid >> 6, l = tid & 63;
    const int lq = l & 31, hi = l >> 5;
    const int hp = blockIdx.y;                 // head-pair 0..15
    const int hk = hp >> 1;                    // kv-head
    const int h  = 2 * hp + (w & 1);           // this wave's q-head
    const int roff = (w >> 1) * 32;            // row offset within 64-row q-tile
    const int bx = blockIdx.x;                 // 0..31
    const int qt = ((hp >> 3) & 1) ? (31 - bx) : bx;
    const int nsteps = (qt + 2) >> 1;          // 128-key steps
    const int qbase = qt * 64;
    const int base = qbase + roff;             // wave's first q-row
    const int qrow = base + lq;                // global q row owned by this lane
    const ushort* Kb = K + (size_t)hk * T * 64;
    const ushort* Vb = Vt + (size_t)hk * 64 * T;

    const int srow = l >> 3;                   // 0..7
    const int sc   = ((l & 7) ^ srow) * 8;     // pre-swizzled global chunk offset

    // Q fragments (B operand): col q = lq, k-dims ks*16 + hi*8 + j
    const ushort* Qrow = Q + ((size_t)h * T + qrow) * 64;
    short8 qf[4];
#pragma unroll
    for (int ks = 0; ks < 4; ++ks)
        qf[ks] = *(const short8*)(Qrow + ks * 16 + hi * 8);

    f32x16 oacc0, oacc1;
#pragma unroll
    for (int r = 0; r < 16; ++r) { oacc0[r] = 0.f; oacc1[r] = 0.f; }
    float ls[4] = {0.f, 0.f, 0.f, 0.f};

    // wave w stages K chunks {2w,2w+1} / V chunks {2w,2w+1} (1KB each) per half
#define ASTAGE(t, buf, half) do { \
    size_t _k0 = (size_t)(t) * 64; \
    const int _c0 = 2 * w, _c1 = 2 * w + 1; \
    gld_lds16(Kb + (_k0 + _c0 * 8 + srow) * 64 + sc, &Ks[buf][half][_c0 * 512]); \
    gld_lds16(Kb + (_k0 + _c1 * 8 + srow) * 64 + sc, &Ks[buf][half][_c1 * 512]); \
    gld_lds16(Vb + (size_t)(_c0 * 8 + srow) * T + _k0 + sc, &Vs[buf][half][_c0 * 512]); \
    gld_lds16(Vb + (size_t)(_c1 * 8 + srow) * T + _k0 + sc, &Vs[buf][half][_c1 * 512]); \
} while (0)

    // R3 tile body, parameterized by (t, buf, half)
#define CTILE(t, bb, hh) do { \
    const bool lastg = ((t) == qt); \
    const bool halfT = lastg && (roff == 0);   /* keys t*64+32.. all masked */ \
    f32x16 s0, s1; \
    _Pragma("unroll") \
    for (int r = 0; r < 16; ++r) { s0[r] = 0.f; s1[r] = 0.f; } \
    __builtin_amdgcn_s_setprio(1); \
    _Pragma("unroll") \
    for (int ks = 0; ks < 4; ++ks) { \
        const int cc = ((ks * 2 + hi) ^ (lq & 7)) * 8; \
        short8 kf0 = *(const short8*)&Ks[bb][hh][lq * 64 + cc]; \
        s0 = MFMA32(kf0, qf[ks], s0); \
    } \
    if (!halfT) { \
        _Pragma("unroll") \
        for (int ks = 0; ks < 4; ++ks) { \
            const int cc = ((ks * 2 + hi) ^ (lq & 7)) * 8; \
            short8 kf1 = *(const short8*)&Ks[bb][hh][(lq + 32) * 64 + cc]; \
            s1 = MFMA32(kf1, qf[ks], s1); \
        } \
    } \
    __builtin_amdgcn_s_setprio(0); \
    const int k0 = (t) * 64; \
    if (lastg) { \
        if (roff == 0) { \
            _Pragma("unroll") \
            for (int r = 0; r < 16; ++r) { \
                const int kk = k0 + (r & 3) + 8 * (r >> 2) + 4 * hi; \
                s0[r] = (kk <= qrow) ? __builtin_amdgcn_exp2f(s0[r]) : 0.f; \
            } \
        } else { \
            _Pragma("unroll") \
            for (int r = 0; r < 16; ++r) s0[r] = __builtin_amdgcn_exp2f(s0[r]); \
            _Pragma("unroll") \
            for (int r = 0; r < 16; ++r) { \
                const int kk = k0 + 32 + (r & 3) + 8 * (r >> 2) + 4 * hi; \
                s1[r] = (kk <= qrow) ? __builtin_amdgcn_exp2f(s1[r]) : 0.f; \
            } \
        } \
    } else { \
        _Pragma("unroll") \
        for (int r = 0; r < 16; ++r) s0[r] = __builtin_amdgcn_exp2f(s0[r]); \
        _Pragma("unroll") \
        for (int r = 0; r < 16; ++r) s1[r] = __builtin_amdgcn_exp2f(s1[r]); \
    } \
    _Pragma("unroll") \
    for (int r = 0; r < 16; ++r) ls[r & 3] += s0[r]; \
    if (!halfT) { \
        _Pragma("unroll") \
        for (int r = 0; r < 16; ++r) ls[r & 3] += s1[r]; \
    } \
    const int nks2 = halfT ? 2 : 4; \
    __builtin_amdgcn_s_setprio(1); \
    for (int ks2 = 0; ks2 < nks2; ++ks2) { \
        const f32x16& pp = (ks2 < 2) ? s0 : s1; \
        const int bse = (ks2 & 1) * 8; \
        unsigned int a0 = cvtpk(pp[bse + 0], pp[bse + 1]); \
        unsigned int a1 = cvtpk(pp[bse + 2], pp[bse + 3]); \
        unsigned int b0 = cvtpk(pp[bse + 4], pp[bse + 5]); \
        unsigned int b1 = cvtpk(pp[bse + 6], pp[bse + 7]); \
        plswap(a0, b0); \
        plswap(a1, b1); \
        u32x4 tw = {a0, a1, b0, b1}; \
        short8 pf = __builtin_bit_cast(short8, tw); \
        const int cc = ((ks2 * 2 + hi) ^ (lq & 7)) * 8; \
        short8 vf0 = *(const short8*)&Vs[bb][hh][lq * 64 + cc]; \
        short8 vf1 = *(const short8*)&Vs[bb][hh][(lq + 32) * 64 + cc]; \
        oacc0 = MFMA32(vf0, pf, oacc0); \
        oacc1 = MFMA32(vf1, pf, oacc1); \
    } \
    __builtin_amdgcn_s_setprio(0); \
} while (0)

    // prologue: stage the first 128-key pair (tile 1 may be unused: safe,
    // keys < T always since max staged tile index is 31)
    ASTAGE(0, 0, 0);
    ASTAGE(1, 0, 1);

    for (int s = 0; s < nsteps; ++s) {
        const int b = s & 1;
        __syncthreads();
        if (s + 1 < nsteps) {
            ASTAGE(2 * s + 2, b ^ 1, 0);
            ASTAGE(2 * s + 3, b ^ 1, 1);
        }
        // half 0 (tile 2s): always needed (2s <= qt, and 2s*64 <= base)
        CTILE(2 * s, b, 0);
        // half 1 (tile 2s+1): wave-uniform skip when fully masked
        const int t1 = 2 * s + 1;
        if (t1 * 64 <= base + 31) {
            CTILE(t1, b, 1);
        }
    }
#undef CTILE
#undef ASTAGE

    // denominator: lane + its hi-partner hold the full row sum for q = lq
    float vsum = (ls[0] + ls[1]) + (ls[2] + ls[3]);
    vsum += __shfl_xor(vsum, 32, 64);
    const float inv = 1.f / vsum;

    // O^T lane layout: col = own q-row; rows d = (r&3)+8*(r>>2)+4*hi (+32)
    ushort* cp = ctx + (size_t)qrow * 2048 + h * 64;
#pragma unroll
    for (int g = 0; g < 4; ++g) {
        ushort4 o0, o1;
        o0.x = f2bf(oacc0[4 * g + 0] * inv); o0.y = f2bf(oacc0[4 * g + 1] * inv);
        o0.z = f2bf(oacc0[4 * g + 2] * inv); o0.w = f2bf(oacc0[4 * g + 3] * inv);
        *(ushort4*)&cp[g * 8 + hi * 4] = o0;
        o1.x = f2bf(oacc1[4 * g + 0] * inv); o1.y = f2bf(oacc1[4 * g + 1] * inv);
        o1.z = f2bf(oacc1[4 * g + 2] * inv); o1.w = f2bf(oacc1[4 * g + 3] * inv);
        *(ushort4*)&cp[32 + g * 8 + hi * 4] = o1;
    }
}

// ---------------------------------------------------------------------------
extern "C" void kernel_launch(void* const* d_in, const int* in_sizes, int n_in,
                              void* d_out, int out_size, void* d_ws, size_t ws_size,
                              hipStream_t stream) {
    const float* x  = (const float*)d_in[0];
    const float* Wq = (const float*)d_in[1];
    const float* Wk = (const float*)d_in[2];
    const float* Wv = (const float*)d_in[3];
    const float* Wo = (const float*)d_in[4];
    const int* start_pos = (const int*)d_in[5];
    float* out = (float*)d_out;

    const int T = T_SEQ, D = D_MODEL;
    const int KV = N_KV * HEAD_DIM;  // 512

    char* w = (char*)d_ws;
    float* cosT = (float*)w;            w += (size_t)32 * T * 4;
    float* sinT = (float*)w;            w += (size_t)32 * T * 4;
    ushort* xbf  = (ushort*)w;          w += (size_t)T * D * 2;     // aliased: ctx
    ushort* wqbf = (ushort*)w;          w += (size_t)D * D * 2;
    ushort* wkbf = (ushort*)w;          w += (size_t)KV * D * 2;
    ushort* wvbf = (ushort*)w;          w += (size_t)KV * D * 2;
    ushort* wobf = (ushort*)w;          w += (size_t)D * D * 2;
    ushort* qbf  = (ushort*)w;          w += (size_t)N_HEADS * T * 64 * 2;
    ushort* kbf  = (ushort*)w;          w += (size_t)N_KV * T * 64 * 2;
    ushort* vtbf = (ushort*)w;          w += (size_t)N_KV * 64 * T * 2;
    ushort* ctxbf = xbf;  // x fully consumed by gemm_qkv before attn writes ctx

    cast_rope_kernel<<<dim3(14336 + 256), dim3(256), 0, stream>>>(
        x, Wq, Wk, Wv, Wo, xbf, wqbf, wkbf, wvbf, wobf, cosT, sinT, start_pos, T);

    gemm_qkv<<<dim3(T / 64, (D + 2 * KV) / 128), dim3(256), 0, stream>>>(
        xbf, wqbf, wkbf, wvbf, qbf, kbf, vtbf, cosT, sinT, T, D);

    attn_mfma<<<dim3(32, 16), dim3(256), 0, stream>>>(qbf, kbf, vtbf, ctxbf, T);

    gemm_bt_f32<<<dim3(T / 64, D / 128), dim3(256), 0, stream>>>(ctxbf, wobf, out, T, D, D);
}